// Round 4
// baseline (1398.412 us; speedup 1.0000x reference)
//
#include <hip/hip_runtime.h>
#include <cmath>

#define B_ 2
#define T_ 4096
#define C_ 2048
#define H_ 32
#define N_ 64
#define L_ 64
#define NC_ 64
#define BT_ 8192

// ---------- storage abstraction: fp32 or bf16-in-memory (compute fp32) ----------
template <typename T> struct io;
template <> struct io<float> {
  static __device__ __forceinline__ float  ld (const float* p) { return *p; }
  static __device__ __forceinline__ float4 ld4(const float* p) { return *(const float4*)p; }
  static __device__ __forceinline__ void st (float* p, float v) { *p = v; }
  static __device__ __forceinline__ void st4(float* p, float4 v) { *(float4*)p = v; }
};
template <> struct io<unsigned short> {
  static __device__ __forceinline__ float ld(const unsigned short* p) {
    return __uint_as_float((unsigned)(*p) << 16);
  }
  static __device__ __forceinline__ float4 ld4(const unsigned short* p) {
    ushort4 u = *(const ushort4*)p;
    return make_float4(__uint_as_float((unsigned)u.x << 16),
                       __uint_as_float((unsigned)u.y << 16),
                       __uint_as_float((unsigned)u.z << 16),
                       __uint_as_float((unsigned)u.w << 16));
  }
  static __device__ __forceinline__ unsigned short cvt1(float x) {
    unsigned u = __float_as_uint(x);
    return (unsigned short)((u + 0x7fffu + ((u >> 16) & 1u)) >> 16);
  }
  static __device__ __forceinline__ void st(unsigned short* p, float v) { *p = cvt1(v); }
  static __device__ __forceinline__ void st4(unsigned short* p, float4 v) {
    ushort4 u;
    u.x = cvt1(v.x); u.y = cvt1(v.y); u.z = cvt1(v.z); u.w = cvt1(v.w);
    *(ushort4*)p = u;
  }
};

// broadcast lane `lane`'s value of v to all lanes (v_readlane, VALU only)
static __device__ __forceinline__ float bcast(float v, int lane) {
  return __uint_as_float(__builtin_amdgcn_readlane(__float_as_uint(v), lane));
}

// ---------------- K0: Z = x + (shift(x) - x) * maa_x ----------------
template <typename ST>
static __global__ __launch_bounds__(256) void k0_z(
    const float* __restrict__ hidden, const float* __restrict__ attn_x,
    const float* __restrict__ maa_x, ST* __restrict__ Z) {
  int idx = blockIdx.x * 256 + threadIdx.x;
  int base = idx * 4;
  int bt = base >> 11;           // / C_
  int c  = base & (C_ - 1);
  int t  = bt & (T_ - 1);
  int b  = bt >> 12;
  float4 x = *(const float4*)(hidden + (size_t)base);
  float4 xp;
  if (t == 0) xp = *(const float4*)(attn_x + (size_t)b * C_ + c);
  else        xp = *(const float4*)(hidden + (size_t)base - C_);
  float4 mx = *(const float4*)(maa_x + c);
  float4 z;
  z.x = x.x + (xp.x - x.x) * mx.x;
  z.y = x.y + (xp.y - x.y) * mx.y;
  z.z = x.z + (xp.z - x.z) * mx.z;
  z.w = x.w + (xp.w - x.w) * mx.w;
  io<ST>::st4(Z + (size_t)base, z);
}

// ---------------- K1: P = tanh(Z @ W1[:, :128]) ----------------
// 16 tokens per block (512 blocks). 64 independent FMAs per c-step per wave
// gives the ILP to hide the (scalarized) Z-load and W1-load latency; W1 L2
// re-read drops to 512 MB total.
template <typename ST>
static __global__ __launch_bounds__(128) void k1_p(
    const ST* __restrict__ Z, const float* __restrict__ W1,
    float* __restrict__ P) {
  int j = threadIdx.x;
  int bt0 = blockIdx.x * 16;
  float acc[16];
#pragma unroll
  for (int tk = 0; tk < 16; ++tk) acc[tk] = 0.f;
  for (int c = 0; c < C_; c += 4) {
    float w0 = W1[(size_t)(c + 0) * 160 + j];
    float w1 = W1[(size_t)(c + 1) * 160 + j];
    float w2 = W1[(size_t)(c + 2) * 160 + j];
    float w3 = W1[(size_t)(c + 3) * 160 + j];
#pragma unroll
    for (int tk = 0; tk < 16; ++tk) {
      float4 z4 = io<ST>::ld4(Z + (size_t)(bt0 + tk) * C_ + c);
      acc[tk] = fmaf(z4.x, w0, acc[tk]);
      acc[tk] = fmaf(z4.y, w1, acc[tk]);
      acc[tk] = fmaf(z4.z, w2, acc[tk]);
      acc[tk] = fmaf(z4.w, w3, acc[tk]);
    }
  }
#pragma unroll
  for (int tk = 0; tk < 16; ++tk)
    P[(size_t)(bt0 + tk) * 128 + j] = tanhf(acc[tk]);
}

// ---------------- K2: xw/xk/xv/xr = x + xx*(maa_f + P_f @ W2_f) ----------------
template <typename ST>
static __global__ __launch_bounds__(256) void k2_mix(
    const float* __restrict__ hidden, const float* __restrict__ attn_x,
    const float* __restrict__ P, const float* __restrict__ W2,
    const float* __restrict__ maa_w, const float* __restrict__ maa_k,
    const float* __restrict__ maa_v, const float* __restrict__ maa_r,
    ST* __restrict__ XW, ST* __restrict__ XK,
    ST* __restrict__ XV, ST* __restrict__ XR) {
  int cb = blockIdx.x & 7;
  int tb = blockIdx.x >> 3;
  int c = cb * 256 + threadIdx.x;
  int bt0 = tb * 16;
  float xv_[16], xx_[16];
#pragma unroll
  for (int tk = 0; tk < 16; ++tk) {
    int bt = bt0 + tk;
    float x = hidden[(size_t)bt * C_ + c];
    int t = bt & (T_ - 1);
    int b = bt >> 12;
    float xp = (t == 0) ? attn_x[(size_t)b * C_ + c]
                        : hidden[(size_t)(bt - 1) * C_ + c];
    xv_[tk] = x;
    xx_[tk] = xp - x;
  }
#pragma unroll
  for (int f = 0; f < 4; ++f) {
    const float* mp = (f == 0) ? maa_w : (f == 1) ? maa_k : (f == 2) ? maa_v : maa_r;
    ST* op          = (f == 0) ? XW    : (f == 1) ? XK    : (f == 2) ? XV    : XR;
    float w2r[32];
#pragma unroll
    for (int k = 0; k < 32; ++k) w2r[k] = W2[(size_t)(f * 32 + k) * C_ + c];
    float mf = mp[c];
    for (int tk = 0; tk < 16; ++tk) {
      const float4* p4 = (const float4*)(P + (size_t)(bt0 + tk) * 128 + f * 32);
      float a0 = 0.f, a1 = 0.f, a2 = 0.f, a3 = 0.f;
#pragma unroll
      for (int q = 0; q < 8; ++q) {
        float4 pv = p4[q];
        a0 = fmaf(pv.x, w2r[4 * q + 0], a0);
        a1 = fmaf(pv.y, w2r[4 * q + 1], a1);
        a2 = fmaf(pv.z, w2r[4 * q + 2], a2);
        a3 = fmaf(pv.w, w2r[4 * q + 3], a3);
      }
      float acc = (a0 + a1) + (a2 + a3);
      io<ST>::st(op + (size_t)(bt0 + tk) * C_ + c, xv_[tk] + xx_[tk] * (mf + acc));
    }
  }
}

// ---------------- K3: D1 = tanh(XW @ DW1) ----------------
// 8 tokens per block (1024 blocks): 32 indep FMAs per c-step, DW1 re-read 512 MB.
template <typename ST>
static __global__ __launch_bounds__(64) void k3_d1(
    const ST* __restrict__ XW, const float* __restrict__ DW1,
    float* __restrict__ D1) {
  int j = threadIdx.x;
  int bt0 = blockIdx.x * 8;
  float acc[8];
#pragma unroll
  for (int tk = 0; tk < 8; ++tk) acc[tk] = 0.f;
  for (int c = 0; c < C_; c += 4) {
    float w0 = DW1[(size_t)(c + 0) * 64 + j];
    float w1 = DW1[(size_t)(c + 1) * 64 + j];
    float w2 = DW1[(size_t)(c + 2) * 64 + j];
    float w3 = DW1[(size_t)(c + 3) * 64 + j];
#pragma unroll
    for (int tk = 0; tk < 8; ++tk) {
      float4 z4 = io<ST>::ld4(XW + (size_t)(bt0 + tk) * C_ + c);
      acc[tk] = fmaf(z4.x, w0, acc[tk]);
      acc[tk] = fmaf(z4.y, w1, acc[tk]);
      acc[tk] = fmaf(z4.z, w2, acc[tk]);
      acc[tk] = fmaf(z4.w, w3, acc[tk]);
    }
  }
#pragma unroll
  for (int tk = 0; tk < 8; ++tk)
    D1[(size_t)(bt0 + tk) * 64 + j] = tanhf(acc[tk]);
}

// ---------------- K4: DEC = exp(-exp(time_decay + D1 @ DW2)) ----------------
template <typename ST>
static __global__ __launch_bounds__(256) void k4_decay(
    const float* __restrict__ D1, const float* __restrict__ DW2,
    const float* __restrict__ td, ST* __restrict__ DEC) {
  int cb = blockIdx.x & 7;
  int tb = blockIdx.x >> 3;
  int c = cb * 256 + threadIdx.x;
  int bt0 = tb * 16;
  float w2r[64];
#pragma unroll
  for (int k = 0; k < 64; ++k) w2r[k] = DW2[(size_t)k * C_ + c];
  float tdv = td[c];
  for (int tk = 0; tk < 16; ++tk) {
    const float4* d4 = (const float4*)(D1 + (size_t)(bt0 + tk) * 64);
    float a0 = 0.f, a1 = 0.f, a2 = 0.f, a3 = 0.f;
#pragma unroll
    for (int q = 0; q < 16; ++q) {
      float4 dv = d4[q];
      a0 = fmaf(dv.x, w2r[4 * q + 0], a0);
      a1 = fmaf(dv.y, w2r[4 * q + 1], a1);
      a2 = fmaf(dv.z, w2r[4 * q + 2], a2);
      a3 = fmaf(dv.w, w2r[4 * q + 3], a3);
    }
    float w = tdv + (a0 + a1) + (a2 + a3);
    io<ST>::st(DEC + (size_t)(bt0 + tk) * C_ + c, expf(-expf(w)));
  }
}

// ---------------- K5: intra-chunk recurrence, register-broadcast version ----------------
// 4 chunks per 256-thread block (one wave per chunk, no cross-wave comms).
// Per t: 4 coalesced per-lane loads; all channel broadcasts via v_readlane.
// y_m = u*v_m*(sum_n r_n k_n) + sum_n r_n s[n,m];  s[n,m] = w_n s[n,m] + k_n v_m.
template <typename ST>
static __global__ __launch_bounds__(256) void k5_intra(
    ST* XRQ,
    const ST* __restrict__ XK, const ST* __restrict__ XV,
    const ST* __restrict__ DEC, const float* __restrict__ faaaa,
    ST* __restrict__ UC, float* __restrict__ DCp, float* __restrict__ Y) {
  int m = threadIdx.x & 63;
  int chunk = blockIdx.x * 4 + (threadIdx.x >> 6);
  int cc = chunk & (NC_ - 1);
  int h = (chunk >> 6) & (H_ - 1);
  int b = chunk >> 11;
  float u = faaaa[h];
  float s[64];
#pragma unroll
  for (int n = 0; n < 64; ++n) s[n] = 0.f;
  float areg = 1.f;
  size_t row = ((size_t)(b * T_ + cc * L_)) * C_ + h * N_;
  for (int t = 0; t < L_; ++t, row += C_) {
    float vm = io<ST>::ld(XV + row + m);
    float wl = io<ST>::ld(DEC + row + m);
    float kl = io<ST>::ld(XK + row + m);
    float rl = io<ST>::ld((const ST*)XRQ + row + m);
    // dot = sum_n r_n k_n (butterfly across the wave)
    float dot = rl * kl;
#pragma unroll
    for (int mk = 32; mk >= 1; mk >>= 1) dot += __shfl_xor(dot, mk, 64);
    float y0 = u * vm * dot, y1 = 0.f, y2 = 0.f, y3 = 0.f;
#pragma unroll
    for (int n = 0; n < 64; n += 4) {
      float rn, kn, wn;
      rn = bcast(rl, n + 0); kn = bcast(kl, n + 0); wn = bcast(wl, n + 0);
      y0 = fmaf(rn, s[n + 0], y0); s[n + 0] = fmaf(wn, s[n + 0], kn * vm);
      rn = bcast(rl, n + 1); kn = bcast(kl, n + 1); wn = bcast(wl, n + 1);
      y1 = fmaf(rn, s[n + 1], y1); s[n + 1] = fmaf(wn, s[n + 1], kn * vm);
      rn = bcast(rl, n + 2); kn = bcast(kl, n + 2); wn = bcast(wl, n + 2);
      y2 = fmaf(rn, s[n + 2], y2); s[n + 2] = fmaf(wn, s[n + 2], kn * vm);
      rn = bcast(rl, n + 3); kn = bcast(kl, n + 3); wn = bcast(wl, n + 3);
      y3 = fmaf(rn, s[n + 3], y3); s[n + 3] = fmaf(wn, s[n + 3], kn * vm);
    }
    io<ST>::st(XRQ + row + m, rl * areg);   // RQ = r * cumdecay (pre-step)
    areg *= wl;
    Y[row + m] = (y0 + y1) + (y2 + y3);
  }
  size_t ucb = (size_t)chunk * (N_ * N_);
#pragma unroll
  for (int n = 0; n < 64; ++n) io<ST>::st(UC + ucb + (size_t)n * 64 + m, s[n]);
  DCp[(size_t)chunk * N_ + m] = areg;
}

// ---------------- K6: inter-chunk state scan (in-place: UC[c] <- state at chunk start) ----
template <typename ST>
static __global__ __launch_bounds__(256) void k6_scan(
    const float* __restrict__ attn_kv, ST* __restrict__ UC,
    const float* __restrict__ DCp) {
  int msel = blockIdx.x & 3;
  int bh = blockIdx.x >> 2;
  int ml = threadIdx.x & 15;
  int n0 = threadIdx.x >> 4;
  int m = msel * 16 + ml;
  float s[4];
#pragma unroll
  for (int i = 0; i < 4; ++i) {
    int n = n0 + 16 * i;
    s[i] = attn_kv[((size_t)bh * N_ + n) * N_ + m];
  }
  for (int c = 0; c < NC_; ++c) {
    size_t cb = (size_t)bh * NC_ + c;
#pragma unroll
    for (int i = 0; i < 4; ++i) {
      int n = n0 + 16 * i;
      size_t idx = (cb * (size_t)(N_ * N_)) + (size_t)n * 64 + m;
      float uc = io<ST>::ld(UC + idx);
      float dc = DCp[cb * N_ + n];
      io<ST>::st(UC + idx, s[i]);
      s[i] = fmaf(dc, s[i], uc);
    }
  }
}

// ---------------- K7: Y += RQ @ s0, register-broadcast version ----------------
template <typename ST>
static __global__ __launch_bounds__(256) void k7_state(
    const ST* __restrict__ RQ, const ST* __restrict__ UC,
    float* __restrict__ Y) {
  int m = threadIdx.x & 63;
  int chunk = blockIdx.x * 4 + (threadIdx.x >> 6);
  int cc = chunk & (NC_ - 1);
  int h = (chunk >> 6) & (H_ - 1);
  int b = chunk >> 11;
  float sc[64];
  size_t ucb = (size_t)chunk * (N_ * N_);
#pragma unroll
  for (int n = 0; n < 64; ++n) sc[n] = io<ST>::ld(UC + ucb + (size_t)n * 64 + m);
  size_t row = ((size_t)(b * T_ + cc * L_)) * C_ + h * N_;
  for (int t = 0; t < L_; ++t, row += C_) {
    float ql = io<ST>::ld(RQ + row + m);
    float y0 = Y[row + m], y1 = 0.f, y2 = 0.f, y3 = 0.f;
#pragma unroll
    for (int n = 0; n < 64; n += 4) {
      y0 = fmaf(bcast(ql, n + 0), sc[n + 0], y0);
      y1 = fmaf(bcast(ql, n + 1), sc[n + 1], y1);
      y2 = fmaf(bcast(ql, n + 2), sc[n + 2], y2);
      y3 = fmaf(bcast(ql, n + 3), sc[n + 3], y3);
    }
    Y[row + m] = (y0 + y1) + (y2 + y3);
  }
}

// ---------------- host ----------------
template <typename ST>
static void run_all(void* const* d_in, void* d_out, void* d_ws, hipStream_t stream) {
  const float* hidden = (const float*)d_in[0];
  const float* attn_x = (const float*)d_in[1];
  const float* attn_kv = (const float*)d_in[2];
  const float* maa_x = (const float*)d_in[4];
  const float* maa_w = (const float*)d_in[5];
  const float* maa_k = (const float*)d_in[6];
  const float* maa_v = (const float*)d_in[7];
  const float* maa_r = (const float*)d_in[8];
  const float* W1 = (const float*)d_in[10];
  const float* W2 = (const float*)d_in[11];
  const float* tdec = (const float*)d_in[12];
  const float* DW1 = (const float*)d_in[13];
  const float* DW2 = (const float*)d_in[14];
  const float* faaaa = (const float*)d_in[15];

  const size_t BIG = (size_t)BT_ * C_;          // 16.78M elems
  char* p = (char*)d_ws;
  ST* A   = (ST*)p; p += BIG * sizeof(ST);      // Z -> XW -> DEC
  ST* XK  = (ST*)p; p += BIG * sizeof(ST);
  ST* XV  = (ST*)p; p += BIG * sizeof(ST);
  ST* XRQ = (ST*)p; p += BIG * sizeof(ST);      // XR, overwritten by RQ in k5
  ST* UC  = (ST*)p; p += BIG * sizeof(ST);      // B*H*NC*N*N == BT*C elems
  float* P   = (float*)p; p += (size_t)BT_ * 128 * 4;
  float* D1  = (float*)p; p += (size_t)BT_ * 64 * 4;
  float* DCp = (float*)p;
  float* Y = (float*)d_out;

  k0_z<ST>    <<<16384, 256, 0, stream>>>(hidden, attn_x, maa_x, A /*Z*/);
  k1_p<ST>    <<<BT_ / 16, 128, 0, stream>>>(A /*Z*/, W1, P);
  k2_mix<ST>  <<<(BT_ / 16) * 8, 256, 0, stream>>>(hidden, attn_x, P, W2,
                                                   maa_w, maa_k, maa_v, maa_r,
                                                   A /*XW*/, XK, XV, XRQ /*XR*/);
  k3_d1<ST>   <<<BT_ / 8, 64, 0, stream>>>(A /*XW*/, DW1, D1);
  k4_decay<ST><<<(BT_ / 16) * 8, 256, 0, stream>>>(D1, DW2, tdec, A /*DEC*/);
  k5_intra<ST><<<B_ * H_ * NC_ / 4, 256, 0, stream>>>(XRQ, XK, XV, A /*DEC*/, faaaa,
                                                      UC, DCp, Y);
  k6_scan<ST> <<<B_ * H_ * 4, 256, 0, stream>>>(attn_kv, UC, DCp);
  k7_state<ST><<<B_ * H_ * NC_ / 4, 256, 0, stream>>>(XRQ /*RQ*/, UC, Y);
}

extern "C" void kernel_launch(void* const* d_in, const int* in_sizes, int n_in,
                              void* d_out, int out_size, void* d_ws, size_t ws_size,
                              hipStream_t stream) {
  const size_t BIG = (size_t)BT_ * C_;
  const size_t small = (size_t)BT_ * 128 * 4 + (size_t)BT_ * 64 * 4 +
                       (size_t)B_ * H_ * NC_ * N_ * 4;
  const size_t need_f32 = BIG * 4 * 5 + small;   // ~343 MB
  if (ws_size >= need_f32)
    run_all<float>(d_in, d_out, d_ws, stream);
  else
    run_all<unsigned short>(d_in, d_out, d_ws, stream);  // bf16 storage, ~175 MB
}

// Round 5
// 846.740 us; speedup vs baseline: 1.6515x; 1.6515x over previous
//
#include <hip/hip_runtime.h>
#include <cmath>

#define B_ 2
#define T_ 4096
#define C_ 2048
#define H_ 32
#define N_ 64
#define L_ 64
#define NC_ 64
#define BT_ 8192

// ---------- storage abstraction: fp32 or bf16-in-memory (compute fp32) ----------
template <typename T> struct io;
template <> struct io<float> {
  static __device__ __forceinline__ float  ld (const float* p) { return *p; }
  static __device__ __forceinline__ float4 ld4(const float* p) { return *(const float4*)p; }
  static __device__ __forceinline__ void st (float* p, float v) { *p = v; }
  static __device__ __forceinline__ void st4(float* p, float4 v) { *(float4*)p = v; }
};
template <> struct io<unsigned short> {
  static __device__ __forceinline__ float ld(const unsigned short* p) {
    return __uint_as_float((unsigned)(*p) << 16);
  }
  static __device__ __forceinline__ float4 ld4(const unsigned short* p) {
    ushort4 u = *(const ushort4*)p;
    return make_float4(__uint_as_float((unsigned)u.x << 16),
                       __uint_as_float((unsigned)u.y << 16),
                       __uint_as_float((unsigned)u.z << 16),
                       __uint_as_float((unsigned)u.w << 16));
  }
  static __device__ __forceinline__ unsigned short cvt1(float x) {
    unsigned u = __float_as_uint(x);
    return (unsigned short)((u + 0x7fffu + ((u >> 16) & 1u)) >> 16);
  }
  static __device__ __forceinline__ void st(unsigned short* p, float v) { *p = cvt1(v); }
  static __device__ __forceinline__ void st4(unsigned short* p, float4 v) {
    ushort4 u;
    u.x = cvt1(v.x); u.y = cvt1(v.y); u.z = cvt1(v.z); u.w = cvt1(v.w);
    *(ushort4*)p = u;
  }
};

// broadcast lane `lane`'s value of v to all lanes (v_readlane, VALU only)
static __device__ __forceinline__ float bcast(float v, int lane) {
  return __uint_as_float(__builtin_amdgcn_readlane(__float_as_uint(v), lane));
}

// ---------------- K0: Z = x + (shift(x) - x) * maa_x ----------------
template <typename ST>
static __global__ __launch_bounds__(256) void k0_z(
    const float* __restrict__ hidden, const float* __restrict__ attn_x,
    const float* __restrict__ maa_x, ST* __restrict__ Z) {
  int idx = blockIdx.x * 256 + threadIdx.x;
  int base = idx * 4;
  int bt = base >> 11;           // / C_
  int c  = base & (C_ - 1);
  int t  = bt & (T_ - 1);
  int b  = bt >> 12;
  float4 x = *(const float4*)(hidden + (size_t)base);
  float4 xp;
  if (t == 0) xp = *(const float4*)(attn_x + (size_t)b * C_ + c);
  else        xp = *(const float4*)(hidden + (size_t)base - C_);
  float4 mx = *(const float4*)(maa_x + c);
  float4 z;
  z.x = x.x + (xp.x - x.x) * mx.x;
  z.y = x.y + (xp.y - x.y) * mx.y;
  z.z = x.z + (xp.z - x.z) * mx.z;
  z.w = x.w + (xp.w - x.w) * mx.w;
  io<ST>::st4(Z + (size_t)base, z);
}

// ---------------- K1: P = tanh(Z @ W1[:, :128]) ----------------
// Readlane-broadcast GEMM: block 256 = 4 waves x 4 tokens, grid 512.
// W1 chunk (64 c x 128 j) double-buffered in LDS; z per-lane coalesced loads,
// broadcast via v_readlane (no uniform-load SMEM serialization).
template <typename ST>
static __global__ __launch_bounds__(256) void k1_p(
    const ST* __restrict__ Z, const float* __restrict__ W1,
    float* __restrict__ P) {
  __shared__ float w1s[2][64 * 128];
  int tid = threadIdx.x;
  int lane = tid & 63;
  int wv = tid >> 6;
  int bt0 = blockIdx.x * 16 + wv * 4;
  float acc[4][2];
#pragma unroll
  for (int tk = 0; tk < 4; ++tk) { acc[tk][0] = 0.f; acc[tk][1] = 0.f; }

  // stage chunk 0
#pragma unroll
  for (int q = 0; q < 8; ++q) {
    int idx = q * 256 + tid;            // 0..2047
    int cc = idx >> 5;
    int j4 = (idx & 31) * 4;
    *(float4*)&w1s[0][cc * 128 + j4] = *(const float4*)&W1[(size_t)cc * 160 + j4];
  }
  __syncthreads();

#pragma unroll 1
  for (int ch = 0; ch < 32; ++ch) {
    int c0 = ch * 64;
    int buf = ch & 1;
    // z loads for this chunk (coalesced, per-lane)
    float z0 = io<ST>::ld(Z + (size_t)(bt0 + 0) * C_ + c0 + lane);
    float z1 = io<ST>::ld(Z + (size_t)(bt0 + 1) * C_ + c0 + lane);
    float z2 = io<ST>::ld(Z + (size_t)(bt0 + 2) * C_ + c0 + lane);
    float z3 = io<ST>::ld(Z + (size_t)(bt0 + 3) * C_ + c0 + lane);
    // prefetch next W1 chunk into the other buffer
    if (ch + 1 < 32) {
#pragma unroll
      for (int q = 0; q < 8; ++q) {
        int idx = q * 256 + tid;
        int cc = idx >> 5;
        int j4 = (idx & 31) * 4;
        *(float4*)&w1s[buf ^ 1][cc * 128 + j4] =
            *(const float4*)&W1[(size_t)(c0 + 64 + cc) * 160 + j4];
      }
    }
#pragma unroll
    for (int l = 0; l < 64; ++l) {
      float wa = w1s[buf][l * 128 + lane];
      float wb = w1s[buf][l * 128 + lane + 64];
      float s0 = bcast(z0, l), s1 = bcast(z1, l), s2 = bcast(z2, l), s3 = bcast(z3, l);
      acc[0][0] = fmaf(s0, wa, acc[0][0]); acc[0][1] = fmaf(s0, wb, acc[0][1]);
      acc[1][0] = fmaf(s1, wa, acc[1][0]); acc[1][1] = fmaf(s1, wb, acc[1][1]);
      acc[2][0] = fmaf(s2, wa, acc[2][0]); acc[2][1] = fmaf(s2, wb, acc[2][1]);
      acc[3][0] = fmaf(s3, wa, acc[3][0]); acc[3][1] = fmaf(s3, wb, acc[3][1]);
    }
    __syncthreads();
  }
#pragma unroll
  for (int tk = 0; tk < 4; ++tk) {
    P[(size_t)(bt0 + tk) * 128 + lane]      = tanhf(acc[tk][0]);
    P[(size_t)(bt0 + tk) * 128 + lane + 64] = tanhf(acc[tk][1]);
  }
}

// ---------------- K2: xw/xk/xv/xr = x + xx*(maa_f + P_f @ W2_f) ----------------
template <typename ST>
static __global__ __launch_bounds__(256) void k2_mix(
    const float* __restrict__ hidden, const float* __restrict__ attn_x,
    const float* __restrict__ P, const float* __restrict__ W2,
    const float* __restrict__ maa_w, const float* __restrict__ maa_k,
    const float* __restrict__ maa_v, const float* __restrict__ maa_r,
    ST* __restrict__ XW, ST* __restrict__ XK,
    ST* __restrict__ XV, ST* __restrict__ XR) {
  int cb = blockIdx.x & 7;
  int tb = blockIdx.x >> 3;
  int c = cb * 256 + threadIdx.x;
  int bt0 = tb * 16;
  float xv_[16], xx_[16];
#pragma unroll
  for (int tk = 0; tk < 16; ++tk) {
    int bt = bt0 + tk;
    float x = hidden[(size_t)bt * C_ + c];
    int t = bt & (T_ - 1);
    int b = bt >> 12;
    float xp = (t == 0) ? attn_x[(size_t)b * C_ + c]
                        : hidden[(size_t)(bt - 1) * C_ + c];
    xv_[tk] = x;
    xx_[tk] = xp - x;
  }
#pragma unroll
  for (int f = 0; f < 4; ++f) {
    const float* mp = (f == 0) ? maa_w : (f == 1) ? maa_k : (f == 2) ? maa_v : maa_r;
    ST* op          = (f == 0) ? XW    : (f == 1) ? XK    : (f == 2) ? XV    : XR;
    float w2r[32];
#pragma unroll
    for (int k = 0; k < 32; ++k) w2r[k] = W2[(size_t)(f * 32 + k) * C_ + c];
    float mf = mp[c];
    for (int tk = 0; tk < 16; ++tk) {
      const float4* p4 = (const float4*)(P + (size_t)(bt0 + tk) * 128 + f * 32);
      float a0 = 0.f, a1 = 0.f, a2 = 0.f, a3 = 0.f;
#pragma unroll
      for (int q = 0; q < 8; ++q) {
        float4 pv = p4[q];
        a0 = fmaf(pv.x, w2r[4 * q + 0], a0);
        a1 = fmaf(pv.y, w2r[4 * q + 1], a1);
        a2 = fmaf(pv.z, w2r[4 * q + 2], a2);
        a3 = fmaf(pv.w, w2r[4 * q + 3], a3);
      }
      float acc = (a0 + a1) + (a2 + a3);
      io<ST>::st(op + (size_t)(bt0 + tk) * C_ + c, xv_[tk] + xx_[tk] * (mf + acc));
    }
  }
}

// ---------------- K3: D1 = tanh(XW @ DW1) ----------------
// Same readlane-broadcast template as k1; j-width 64 (one j per lane).
template <typename ST>
static __global__ __launch_bounds__(256) void k3_d1(
    const ST* __restrict__ XW, const float* __restrict__ DW1,
    float* __restrict__ D1) {
  __shared__ float w1s[2][64 * 64];
  int tid = threadIdx.x;
  int lane = tid & 63;
  int wv = tid >> 6;
  int bt0 = blockIdx.x * 16 + wv * 4;
  float acc[4];
#pragma unroll
  for (int tk = 0; tk < 4; ++tk) acc[tk] = 0.f;

#pragma unroll
  for (int q = 0; q < 4; ++q) {
    int idx = q * 256 + tid;            // 0..1023
    int cc = idx >> 4;
    int j4 = (idx & 15) * 4;
    *(float4*)&w1s[0][cc * 64 + j4] = *(const float4*)&DW1[(size_t)cc * 64 + j4];
  }
  __syncthreads();

#pragma unroll 1
  for (int ch = 0; ch < 32; ++ch) {
    int c0 = ch * 64;
    int buf = ch & 1;
    float z0 = io<ST>::ld(XW + (size_t)(bt0 + 0) * C_ + c0 + lane);
    float z1 = io<ST>::ld(XW + (size_t)(bt0 + 1) * C_ + c0 + lane);
    float z2 = io<ST>::ld(XW + (size_t)(bt0 + 2) * C_ + c0 + lane);
    float z3 = io<ST>::ld(XW + (size_t)(bt0 + 3) * C_ + c0 + lane);
    if (ch + 1 < 32) {
#pragma unroll
      for (int q = 0; q < 4; ++q) {
        int idx = q * 256 + tid;
        int cc = idx >> 4;
        int j4 = (idx & 15) * 4;
        *(float4*)&w1s[buf ^ 1][cc * 64 + j4] =
            *(const float4*)&DW1[(size_t)(c0 + 64 + cc) * 64 + j4];
      }
    }
#pragma unroll
    for (int l = 0; l < 64; ++l) {
      float wa = w1s[buf][l * 64 + lane];
      acc[0] = fmaf(bcast(z0, l), wa, acc[0]);
      acc[1] = fmaf(bcast(z1, l), wa, acc[1]);
      acc[2] = fmaf(bcast(z2, l), wa, acc[2]);
      acc[3] = fmaf(bcast(z3, l), wa, acc[3]);
    }
    __syncthreads();
  }
#pragma unroll
  for (int tk = 0; tk < 4; ++tk)
    D1[(size_t)(bt0 + tk) * 64 + lane] = tanhf(acc[tk]);
}

// ---------------- K4: DEC = exp(-exp(time_decay + D1 @ DW2)) ----------------
template <typename ST>
static __global__ __launch_bounds__(256) void k4_decay(
    const float* __restrict__ D1, const float* __restrict__ DW2,
    const float* __restrict__ td, ST* __restrict__ DEC) {
  int cb = blockIdx.x & 7;
  int tb = blockIdx.x >> 3;
  int c = cb * 256 + threadIdx.x;
  int bt0 = tb * 16;
  float w2r[64];
#pragma unroll
  for (int k = 0; k < 64; ++k) w2r[k] = DW2[(size_t)k * C_ + c];
  float tdv = td[c];
  for (int tk = 0; tk < 16; ++tk) {
    const float4* d4 = (const float4*)(D1 + (size_t)(bt0 + tk) * 64);
    float a0 = 0.f, a1 = 0.f, a2 = 0.f, a3 = 0.f;
#pragma unroll
    for (int q = 0; q < 16; ++q) {
      float4 dv = d4[q];
      a0 = fmaf(dv.x, w2r[4 * q + 0], a0);
      a1 = fmaf(dv.y, w2r[4 * q + 1], a1);
      a2 = fmaf(dv.z, w2r[4 * q + 2], a2);
      a3 = fmaf(dv.w, w2r[4 * q + 3], a3);
    }
    float w = tdv + (a0 + a1) + (a2 + a3);
    io<ST>::st(DEC + (size_t)(bt0 + tk) * C_ + c, expf(-expf(w)));
  }
}

// ---------------- K5: intra-chunk recurrence, register-broadcast version ----------------
template <typename ST>
static __global__ __launch_bounds__(256) void k5_intra(
    ST* XRQ,
    const ST* __restrict__ XK, const ST* __restrict__ XV,
    const ST* __restrict__ DEC, const float* __restrict__ faaaa,
    ST* __restrict__ UC, float* __restrict__ DCp, float* __restrict__ Y) {
  int m = threadIdx.x & 63;
  int chunk = blockIdx.x * 4 + (threadIdx.x >> 6);
  int cc = chunk & (NC_ - 1);
  int h = (chunk >> 6) & (H_ - 1);
  int b = chunk >> 11;
  float u = faaaa[h];
  float s[64];
#pragma unroll
  for (int n = 0; n < 64; ++n) s[n] = 0.f;
  float areg = 1.f;
  size_t row = ((size_t)(b * T_ + cc * L_)) * C_ + h * N_;
  for (int t = 0; t < L_; ++t, row += C_) {
    float vm = io<ST>::ld(XV + row + m);
    float wl = io<ST>::ld(DEC + row + m);
    float kl = io<ST>::ld(XK + row + m);
    float rl = io<ST>::ld((const ST*)XRQ + row + m);
    float dot = rl * kl;
#pragma unroll
    for (int mk = 32; mk >= 1; mk >>= 1) dot += __shfl_xor(dot, mk, 64);
    float y0 = u * vm * dot, y1 = 0.f, y2 = 0.f, y3 = 0.f;
#pragma unroll
    for (int n = 0; n < 64; n += 4) {
      float rn, kn, wn;
      rn = bcast(rl, n + 0); kn = bcast(kl, n + 0); wn = bcast(wl, n + 0);
      y0 = fmaf(rn, s[n + 0], y0); s[n + 0] = fmaf(wn, s[n + 0], kn * vm);
      rn = bcast(rl, n + 1); kn = bcast(kl, n + 1); wn = bcast(wl, n + 1);
      y1 = fmaf(rn, s[n + 1], y1); s[n + 1] = fmaf(wn, s[n + 1], kn * vm);
      rn = bcast(rl, n + 2); kn = bcast(kl, n + 2); wn = bcast(wl, n + 2);
      y2 = fmaf(rn, s[n + 2], y2); s[n + 2] = fmaf(wn, s[n + 2], kn * vm);
      rn = bcast(rl, n + 3); kn = bcast(kl, n + 3); wn = bcast(wl, n + 3);
      y3 = fmaf(rn, s[n + 3], y3); s[n + 3] = fmaf(wn, s[n + 3], kn * vm);
    }
    io<ST>::st(XRQ + row + m, rl * areg);   // RQ = r * cumdecay (pre-step)
    areg *= wl;
    Y[row + m] = (y0 + y1) + (y2 + y3);
  }
  size_t ucb = (size_t)chunk * (N_ * N_);
#pragma unroll
  for (int n = 0; n < 64; ++n) io<ST>::st(UC + ucb + (size_t)n * 64 + m, s[n]);
  DCp[(size_t)chunk * N_ + m] = areg;
}

// ---------------- K6: inter-chunk state scan ----------------
template <typename ST>
static __global__ __launch_bounds__(256) void k6_scan(
    const float* __restrict__ attn_kv, ST* __restrict__ UC,
    const float* __restrict__ DCp) {
  int msel = blockIdx.x & 3;
  int bh = blockIdx.x >> 2;
  int ml = threadIdx.x & 15;
  int n0 = threadIdx.x >> 4;
  int m = msel * 16 + ml;
  float s[4];
#pragma unroll
  for (int i = 0; i < 4; ++i) {
    int n = n0 + 16 * i;
    s[i] = attn_kv[((size_t)bh * N_ + n) * N_ + m];
  }
  for (int c = 0; c < NC_; ++c) {
    size_t cb = (size_t)bh * NC_ + c;
#pragma unroll
    for (int i = 0; i < 4; ++i) {
      int n = n0 + 16 * i;
      size_t idx = (cb * (size_t)(N_ * N_)) + (size_t)n * 64 + m;
      float uc = io<ST>::ld(UC + idx);
      float dc = DCp[cb * N_ + n];
      io<ST>::st(UC + idx, s[i]);
      s[i] = fmaf(dc, s[i], uc);
    }
  }
}

// ---------------- K7: Y += RQ @ s0 ----------------
template <typename ST>
static __global__ __launch_bounds__(256) void k7_state(
    const ST* __restrict__ RQ, const ST* __restrict__ UC,
    float* __restrict__ Y) {
  int m = threadIdx.x & 63;
  int chunk = blockIdx.x * 4 + (threadIdx.x >> 6);
  int cc = chunk & (NC_ - 1);
  int h = (chunk >> 6) & (H_ - 1);
  int b = chunk >> 11;
  float sc[64];
  size_t ucb = (size_t)chunk * (N_ * N_);
#pragma unroll
  for (int n = 0; n < 64; ++n) sc[n] = io<ST>::ld(UC + ucb + (size_t)n * 64 + m);
  size_t row = ((size_t)(b * T_ + cc * L_)) * C_ + h * N_;
  for (int t = 0; t < L_; ++t, row += C_) {
    float ql = io<ST>::ld(RQ + row + m);
    float y0 = Y[row + m], y1 = 0.f, y2 = 0.f, y3 = 0.f;
#pragma unroll
    for (int n = 0; n < 64; n += 4) {
      y0 = fmaf(bcast(ql, n + 0), sc[n + 0], y0);
      y1 = fmaf(bcast(ql, n + 1), sc[n + 1], y1);
      y2 = fmaf(bcast(ql, n + 2), sc[n + 2], y2);
      y3 = fmaf(bcast(ql, n + 3), sc[n + 3], y3);
    }
    Y[row + m] = (y0 + y1) + (y2 + y3);
  }
}

// ---------------- host ----------------
template <typename ST>
static void run_all(void* const* d_in, void* d_out, void* d_ws, hipStream_t stream) {
  const float* hidden = (const float*)d_in[0];
  const float* attn_x = (const float*)d_in[1];
  const float* attn_kv = (const float*)d_in[2];
  const float* maa_x = (const float*)d_in[4];
  const float* maa_w = (const float*)d_in[5];
  const float* maa_k = (const float*)d_in[6];
  const float* maa_v = (const float*)d_in[7];
  const float* maa_r = (const float*)d_in[8];
  const float* W1 = (const float*)d_in[10];
  const float* W2 = (const float*)d_in[11];
  const float* tdec = (const float*)d_in[12];
  const float* DW1 = (const float*)d_in[13];
  const float* DW2 = (const float*)d_in[14];
  const float* faaaa = (const float*)d_in[15];

  const size_t BIG = (size_t)BT_ * C_;          // 16.78M elems
  char* p = (char*)d_ws;
  ST* A   = (ST*)p; p += BIG * sizeof(ST);      // Z -> XW -> DEC
  ST* XK  = (ST*)p; p += BIG * sizeof(ST);
  ST* XV  = (ST*)p; p += BIG * sizeof(ST);
  ST* XRQ = (ST*)p; p += BIG * sizeof(ST);      // XR, overwritten by RQ in k5
  ST* UC  = (ST*)p; p += BIG * sizeof(ST);      // B*H*NC*N*N == BT*C elems
  float* P   = (float*)p; p += (size_t)BT_ * 128 * 4;
  float* D1  = (float*)p; p += (size_t)BT_ * 64 * 4;
  float* DCp = (float*)p;
  float* Y = (float*)d_out;

  k0_z<ST>    <<<16384, 256, 0, stream>>>(hidden, attn_x, maa_x, A /*Z*/);
  k1_p<ST>    <<<BT_ / 16, 256, 0, stream>>>(A /*Z*/, W1, P);
  k2_mix<ST>  <<<(BT_ / 16) * 8, 256, 0, stream>>>(hidden, attn_x, P, W2,
                                                   maa_w, maa_k, maa_v, maa_r,
                                                   A /*XW*/, XK, XV, XRQ /*XR*/);
  k3_d1<ST>   <<<BT_ / 16, 256, 0, stream>>>(A /*XW*/, DW1, D1);
  k4_decay<ST><<<(BT_ / 16) * 8, 256, 0, stream>>>(D1, DW2, tdec, A /*DEC*/);
  k5_intra<ST><<<B_ * H_ * NC_ / 4, 256, 0, stream>>>(XRQ, XK, XV, A /*DEC*/, faaaa,
                                                      UC, DCp, Y);
  k6_scan<ST> <<<B_ * H_ * 4, 256, 0, stream>>>(attn_kv, UC, DCp);
  k7_state<ST><<<B_ * H_ * NC_ / 4, 256, 0, stream>>>(XRQ /*RQ*/, UC, Y);
}

extern "C" void kernel_launch(void* const* d_in, const int* in_sizes, int n_in,
                              void* d_out, int out_size, void* d_ws, size_t ws_size,
                              hipStream_t stream) {
  const size_t BIG = (size_t)BT_ * C_;
  const size_t small = (size_t)BT_ * 128 * 4 + (size_t)BT_ * 64 * 4 +
                       (size_t)B_ * H_ * NC_ * N_ * 4;
  const size_t need_f32 = BIG * 4 * 5 + small;   // ~343 MB
  if (ws_size >= need_f32)
    run_all<float>(d_in, d_out, d_ws, stream);
  else
    run_all<unsigned short>(d_in, d_out, d_ws, stream);  // bf16 storage, ~175 MB
}